// Round 4
// baseline (458.219 us; speedup 1.0000x reference)
//
#include <hip/hip_runtime.h>

// HierarchicalSoftmax: out[b, c*320 + t] = (x_b · topW[:,c] + top_b[c]) + (x_b · botW[t,:] + bot_b[t])
// B=1024, NHID=128, NCLASSES=320, PER_CLASS=320, row = 102400 fp32, out = 419.4 MB.
//
// R1 findings: timed dur includes a fixed ~270.8 us harness re-poison fill (6.2 TB/s memset on
// this buffer!); actual kernel ~171 us (2.45 TB/s). Fused phase1->barrier->phase2 structure
// serializes compute bursts with the store stream 2048 times. De-fuse:
//   K1: all 640 logits/row -> ws (2.62 MB, ~10 us).
//   K2: memset-shaped grid-stride stream: 2 L2-hot loads + add + store, zero barriers/tail.
// Target: K2 ~70-95 us -> dur ~350-365. Floor = 270.8 (fill) + 67 (write BW) = ~338.
// (R3: second resubmission — GPU acquisition timed out twice; never measured.)

#define BATCH      1024
#define NHID       128
#define NCLASSES   320
#define PER_CLASS  320
#define ROW_ELEMS  (NCLASSES * PER_CLASS)    // 102400
#define ROW_F4     (ROW_ELEMS / 4)           // 25600
#define PC_F4      (PER_CLASS / 4)           // 80
#define LPR        (NCLASSES + PER_CLASS)    // 640 logits per row
#define LPR_F4     (LPR / 4)                 // 160
#define WS_BYTES   ((size_t)BATCH * LPR * sizeof(float))  // 2.62 MB

#define STHREADS   256
#define SGRID      2048
#define TOTAL_F4   (BATCH * ROW_F4)          // 26,214,400
#define SSTRIDE    (SGRID * STHREADS)        // 524,288
#define SITERS     (TOTAL_F4 / SSTRIDE)      // 50 exactly -> no tail, no bounds check

typedef float f32x4 __attribute__((ext_vector_type(4)));

// ---------------- K1: logits -> ws[b*640 + {c | 320+t}] ----------------
__global__ __launch_bounds__(LPR) void hs_logits_kernel(
    const float* __restrict__ inputs,     // [B, NHID]
    const float* __restrict__ top_W,      // [NHID, NCLASSES] (k-major)
    const float* __restrict__ top_b,      // [NCLASSES]
    const float* __restrict__ bottom_W,   // [PER_CLASS, NHID]
    const float* __restrict__ bottom_b,   // [PER_CLASS]
    float* __restrict__ ws)               // [B, 640]
{
    __shared__ __align__(16) float s_in[NHID];
    const int b   = blockIdx.x;
    const int tid = threadIdx.x;          // 0..639, exactly one dot each

    if (tid < NHID) s_in[tid] = inputs[b * NHID + tid];
    __syncthreads();

    float acc;
    if (tid < NCLASSES) {
        acc = top_b[tid];
        #pragma unroll 8
        for (int k = 0; k < NHID; ++k)
            acc += s_in[k] * top_W[k * NCLASSES + tid];      // coalesced across tid
    } else {
        const int t = tid - NCLASSES;
        acc = bottom_b[t];
        const f32x4* w4 = (const f32x4*)(bottom_W + t * NHID);
        #pragma unroll 8
        for (int k4 = 0; k4 < NHID / 4; ++k4) {
            f32x4 w = w4[k4];
            acc += s_in[4*k4+0]*w.x + s_in[4*k4+1]*w.y
                 + s_in[4*k4+2]*w.z + s_in[4*k4+3]*w.w;
        }
    }
    ws[b * LPR + tid] = acc;
}

// ---------------- K2: pure stream, memset-shaped ----------------
// out4[g] = ws_top[g/25600][ (g%25600)/80 ] + ws_bot4[g/25600][ (g%25600)%80 ]
__global__ __launch_bounds__(STHREADS, 8) void hs_stream_kernel(
    const float* __restrict__ ws,         // [B, 640]; 2.62 MB -> L2-resident
    float* __restrict__ out)
{
    const f32x4* __restrict__ ws4  = (const f32x4*)ws;
    f32x4* __restrict__ out4 = (f32x4*)out;

    unsigned g = blockIdx.x * STHREADS + threadIdx.x;
    #pragma unroll 5
    for (int it = 0; it < SITERS; ++it, g += SSTRIDE) {
        const unsigned b  = g / ROW_F4;          // magic mul
        const unsigned r  = g - b * ROW_F4;
        const unsigned c  = r / PC_F4;           // magic mul
        const unsigned t4 = r - c * PC_F4;
        const float tv = ws[b * LPR + c];                      // 1-2 lines/wave, L1/L2 hit
        const f32x4 bv = ws4[b * LPR_F4 + (NCLASSES/4) + t4];  // coalesced 16B/lane, L2 hit
        f32x4 v;
        v.x = tv + bv.x;
        v.y = tv + bv.y;
        v.z = tv + bv.z;
        v.w = tv + bv.w;
        out4[g] = v;                                           // contiguous wave store, 1KB
    }
}

// ---------------- fallback (R1 fused kernel) if ws unavailable ----------------
#define HALVES      2
#define CLS_PER_BLK (NCLASSES / HALVES)
#define FTHREADS    320
#define C_PER_ITER  (FTHREADS / PC_F4)
#define NITER       (CLS_PER_BLK / C_PER_ITER)

__global__ __launch_bounds__(FTHREADS) void hs_fused_kernel(
    const float* __restrict__ inputs, const float* __restrict__ top_W,
    const float* __restrict__ top_b, const float* __restrict__ bottom_W,
    const float* __restrict__ bottom_b, float* __restrict__ out)
{
    __shared__ __align__(16) float s_in[NHID];
    __shared__ float s_top[CLS_PER_BLK];
    __shared__ __align__(16) float s_bot[PER_CLASS];
    const int b = blockIdx.x, h = blockIdx.y, tid = threadIdx.x;
    if (tid < NHID) s_in[tid] = inputs[b * NHID + tid];
    __syncthreads();
    for (int j = tid; j < CLS_PER_BLK + PER_CLASS; j += FTHREADS) {
        float acc;
        if (j < CLS_PER_BLK) {
            const int c = h * CLS_PER_BLK + j;
            acc = top_b[c];
            #pragma unroll 8
            for (int k = 0; k < NHID; ++k) acc += s_in[k] * top_W[k * NCLASSES + c];
            s_top[j] = acc;
        } else {
            const int t = j - CLS_PER_BLK;
            acc = bottom_b[t];
            const f32x4* w4 = (const f32x4*)(bottom_W + t * NHID);
            #pragma unroll 8
            for (int k4 = 0; k4 < NHID / 4; ++k4) {
                f32x4 w = w4[k4];
                acc += s_in[4*k4+0]*w.x + s_in[4*k4+1]*w.y + s_in[4*k4+2]*w.z + s_in[4*k4+3]*w.w;
            }
            s_bot[t] = acc;
        }
    }
    __syncthreads();
    const int c_off = tid / PC_F4;
    const int t4    = tid - c_off * PC_F4;
    const f32x4 bv  = ((const f32x4*)s_bot)[t4];
    f32x4* outp = (f32x4*)out + (size_t)b * ROW_F4 + h * (CLS_PER_BLK * PC_F4) + c_off * PC_F4 + t4;
    #pragma unroll 8
    for (int it = 0; it < NITER; ++it) {
        const float tv = s_top[it * C_PER_ITER + c_off];
        f32x4 v;
        v.x = tv + bv.x; v.y = tv + bv.y; v.z = tv + bv.z; v.w = tv + bv.w;
        outp[it * (C_PER_ITER * PC_F4)] = v;
    }
}

extern "C" void kernel_launch(void* const* d_in, const int* in_sizes, int n_in,
                              void* d_out, int out_size, void* d_ws, size_t ws_size,
                              hipStream_t stream) {
    const float* inputs   = (const float*)d_in[0];
    const float* top_W    = (const float*)d_in[1];
    const float* top_b    = (const float*)d_in[2];
    const float* bottom_W = (const float*)d_in[3];
    const float* bottom_b = (const float*)d_in[4];
    float* out = (float*)d_out;

    if (d_ws != nullptr && ws_size >= WS_BYTES) {
        float* ws = (float*)d_ws;
        hs_logits_kernel<<<BATCH, LPR, 0, stream>>>(inputs, top_W, top_b, bottom_W, bottom_b, ws);
        hs_stream_kernel<<<SGRID, STHREADS, 0, stream>>>(ws, out);
    } else {
        hs_fused_kernel<<<dim3(BATCH, HALVES), FTHREADS, 0, stream>>>(
            inputs, top_W, top_b, bottom_W, bottom_b, out);
    }
}